// Round 1
// baseline (116.680 us; speedup 1.0000x reference)
//
#include <hip/hip_runtime.h>
#include <math.h>

// Problem constants (match reference)
static constexpr int kB = 128;
static constexpr int kN = 8732;
static constexpr int kC = 25;          // 4 loc + 21 cls
static constexpr int kNC = 21;         // num classes incl. background
static constexpr int ROWS = 256;       // rows (anchors) per block
static constexpr int CHUNKS = (kN + ROWS - 1) / ROWS;  // 35

__global__ __launch_bounds__(128) void zero_num_kernel(float* __restrict__ numf) {
    int t = threadIdx.x;
    if (t < kB) numf[t] = 0.0f;
}

__global__ __launch_bounds__(256) void decode_kernel(
    const float* __restrict__ logits,   // [B, N, 25]
    const float* __restrict__ anchors,  // [N, 4]
    float* __restrict__ boxes,          // [B, N, 4]
    float* __restrict__ scores,         // [B, N]
    float* __restrict__ classesf,       // [B, N] (float-encoded int)
    float* __restrict__ validf,         // [B, N] (float-encoded bool)
    float* __restrict__ numf)           // [B]    (float-encoded int)
{
    __shared__ float lds[ROWS * kC];    // 25.6 KB

    const int chunk = blockIdx.x;       // [0, 35)
    const int b     = blockIdx.y;       // [0, 128)
    const int row0  = chunk * ROWS;
    const int nrows = min(ROWS, kN - row0);
    const long grow0 = (long)b * kN + row0;   // global row index of this block's first row

    // ---- Stage this block's logits rows into LDS, coalesced float4 ----
    // byte offset = grow0*25*4; grow0 % 4 == 0 (8732 and 256 both %4==0) -> 16B aligned
    {
        const float4* __restrict__ src = (const float4*)(logits + grow0 * kC);
        float4* dst = (float4*)lds;
        const int nvec = (nrows * kC) / 4;   // nrows*25 always divisible by 4 (nrows%4==0)
        for (int i = threadIdx.x; i < nvec; i += 256)
            dst[i] = src[i];
        // tail floats if nrows*25 % 4 != 0 (never happens: nrows is 256 or 28)
    }
    __syncthreads();

    const int r = threadIdx.x;
    const bool inR = (r < nrows);
    bool valid = false;

    if (inR) {
        const float* __restrict__ L = lds + r * kC;
        const int n = row0 + r;
        const long bn = grow0 + r;

        // anchors: coalesced float4
        const float4 a = ((const float4*)anchors)[n];
        const float cx = 0.5f * (a.x + a.z);
        const float cy = 0.5f * (a.y + a.w);
        const float w  = a.z - a.x;
        const float h  = a.w - a.y;

        // decode box
        const float xc = L[0] * w + cx;
        const float yc = L[1] * h + cy;
        const float bw = expf(L[2]) * w;
        const float bh = expf(L[3]) * h;

        float x0 = xc - 0.5f * bw;
        float y0 = yc - 0.5f * bh;
        float x1 = xc + 0.5f * bw;
        float y1 = yc + 0.5f * bh;
        x0 = fminf(fmaxf(x0, 0.0f), 1.0f);
        y0 = fminf(fmaxf(y0, 0.0f), 1.0f);
        x1 = fminf(fmaxf(x1, 0.0f), 1.0f);
        y1 = fminf(fmaxf(y1, 0.0f), 1.0f);

        // max / argmax over 21 classes (first-max tie-break like jnp.argmax)
        float best = L[4];
        int   bidx = 0;
        #pragma unroll
        for (int j = 1; j < kNC; ++j) {
            const float v = L[4 + j];
            if (v > best) { best = v; bidx = j; }
        }
        valid = (bidx != 0);

        // stores (boxes as float4, 16B-aligned per row)
        ((float4*)boxes)[bn] = make_float4(x0, y0, x1, y1);
        scores[bn]   = best;
        classesf[bn] = (float)bidx;
        validf[bn]   = valid ? 1.0f : 0.0f;
    }

    // per-wave popcount of valid, one atomic per wave
    const unsigned long long m = __ballot(valid);
    if ((threadIdx.x & 63) == 0) {
        const float cnt = (float)__popcll(m);
        if (cnt > 0.0f) atomicAdd(&numf[b], cnt);
    }
}

extern "C" void kernel_launch(void* const* d_in, const int* in_sizes, int n_in,
                              void* d_out, int out_size, void* d_ws, size_t ws_size,
                              hipStream_t stream) {
    const float* logits  = (const float*)d_in[0];
    const float* anchors = (const float*)d_in[1];

    float* out = (float*)d_out;
    const long BN = (long)kB * kN;
    float* boxes    = out;                 // 4*BN
    float* scores   = boxes + 4 * BN;      // BN
    float* classesf = scores + BN;         // BN
    float* validf   = classesf + BN;       // BN
    float* numf     = validf + BN;         // B

    zero_num_kernel<<<1, 128, 0, stream>>>(numf);
    dim3 grid(CHUNKS, kB);
    decode_kernel<<<grid, 256, 0, stream>>>(logits, anchors, boxes, scores,
                                            classesf, validf, numf);
}

// Round 2
// 66.756 us; speedup vs baseline: 1.7479x; 1.7479x over previous
//
#include <hip/hip_runtime.h>
#include <math.h>

// Problem constants (match reference)
static constexpr int kB  = 128;
static constexpr int kN  = 8732;
static constexpr int kC  = 25;     // 4 loc + 21 cls
static constexpr int kNC = 21;     // num classes incl. background
static constexpr int TR  = 128;    // rows per block (one wave)
static constexpr int CH  = (kN + TR - 1) / TR;   // 69
static constexpr int NV2_FULL = TR * kC / 2;     // 1600 float2 per full tile (25/lane)

__global__ __launch_bounds__(128) void zero_num_kernel(float* __restrict__ numf) {
    int t = threadIdx.x;
    if (t < kB) numf[t] = 0.0f;
}

__global__ __launch_bounds__(64) void decode_kernel(
    const float* __restrict__ logits,   // [B, N, 25]
    const float* __restrict__ anchors,  // [N, 4]
    float* __restrict__ boxes,          // [B, N, 4]
    float* __restrict__ scores,         // [B, N]
    float* __restrict__ classesf,       // [B, N]
    float* __restrict__ validf,         // [B, N]
    float* __restrict__ numf)           // [B]
{
    __shared__ float lds[TR * kC];      // 12.8 KB, wave-private (1 wave/block)

    const int chunk = blockIdx.x;       // [0, 69)
    const int b     = blockIdx.y;       // [0, 128)
    const int row0  = chunk * TR;
    const int nrows = min(TR, kN - row0);
    const long grow0 = (long)b * kN + row0;  // grow0 even -> *100B is 8-aligned
    const int l = threadIdx.x;          // lane 0..63

    // ---- Stage tile into LDS: 25 dwordx2 loads per lane, all in flight ----
    const float2* __restrict__ src = (const float2*)(logits + grow0 * kC);
    float2* dst = (float2*)lds;
    if (nrows == TR) {
        float2 v[25];
        #pragma unroll
        for (int k = 0; k < 25; ++k) v[k] = src[l + 64 * k];   // issued back-to-back
        #pragma unroll
        for (int k = 0; k < 25; ++k) dst[l + 64 * k] = v[k];
    } else {
        const int nvec = nrows * kC / 2;  // nrows even (28)
        #pragma unroll
        for (int k = 0; k < 25; ++k) {
            const int i = l + 64 * k;
            if (i < nvec) dst[i] = src[i];
        }
    }
    __syncthreads();   // single-wave block: compiles to lgkmcnt wait, no drain

    int cnt = 0;
    #pragma unroll
    for (int j = 0; j < 2; ++j) {
        const int r = l + 64 * j;       // rows {l, l+64}: unit-stride stores
        if (r < nrows) {
            const float* __restrict__ L = lds + r * kC;  // stride 25 dwords: 0 bank conflicts
            const int n = row0 + r;
            const long bn = grow0 + r;

            const float4 a = ((const float4*)anchors)[n];
            const float cx = 0.5f * (a.x + a.z);
            const float cy = 0.5f * (a.y + a.w);
            const float w  = a.z - a.x;
            const float h  = a.w - a.y;

            const float xc = L[0] * w + cx;
            const float yc = L[1] * h + cy;
            const float bw = expf(L[2]) * w;
            const float bh = expf(L[3]) * h;

            float x0 = fminf(fmaxf(xc - 0.5f * bw, 0.0f), 1.0f);
            float y0 = fminf(fmaxf(yc - 0.5f * bh, 0.0f), 1.0f);
            float x1 = fminf(fmaxf(xc + 0.5f * bw, 0.0f), 1.0f);
            float y1 = fminf(fmaxf(yc + 0.5f * bh, 0.0f), 1.0f);

            // max/argmax over 21 classes, first-max tie-break (jnp.argmax)
            float best = L[4];
            int   bidx = 0;
            #pragma unroll
            for (int c = 1; c < kNC; ++c) {
                const float v = L[4 + c];
                if (v > best) { best = v; bidx = c; }
            }
            const bool valid = (bidx != 0);
            cnt += valid ? 1 : 0;

            ((float4*)boxes)[bn] = make_float4(x0, y0, x1, y1);
            scores[bn]   = best;
            classesf[bn] = (float)bidx;
            validf[bn]   = valid ? 1.0f : 0.0f;
        }
    }

    // one atomic per wave: sum of this wave's valid count (both row batches)
    // reduce across lanes via ballot-free popcount: use shuffle-free ballots
    unsigned long long m0 = __ballot(cnt >= 1);
    unsigned long long m1 = __ballot(cnt == 2);
    if (l == 0) {
        const float c = (float)(__popcll(m0) + __popcll(m1));
        if (c > 0.0f) atomicAdd(&numf[b], c);
    }
}

extern "C" void kernel_launch(void* const* d_in, const int* in_sizes, int n_in,
                              void* d_out, int out_size, void* d_ws, size_t ws_size,
                              hipStream_t stream) {
    const float* logits  = (const float*)d_in[0];
    const float* anchors = (const float*)d_in[1];

    float* out = (float*)d_out;
    const long BN = (long)kB * kN;
    float* boxes    = out;                 // 4*BN
    float* scores   = boxes + 4 * BN;      // BN
    float* classesf = scores + BN;         // BN
    float* validf   = classesf + BN;       // BN
    float* numf     = validf + BN;         // B

    zero_num_kernel<<<1, 128, 0, stream>>>(numf);
    dim3 grid(CH, kB);
    decode_kernel<<<grid, 64, 0, stream>>>(logits, anchors, boxes, scores,
                                           classesf, validf, numf);
}